// Round 9
// baseline (616.208 us; speedup 1.0000x reference)
//
#include <hip/hip_runtime.h>
#include <hip/hip_bf16.h>
#include <cstdint>
#include <cstddef>

typedef __bf16 bf16x8 __attribute__((ext_vector_type(8)));
typedef float  f32x4  __attribute__((ext_vector_type(4)));

typedef const __attribute__((address_space(1))) unsigned int gu32;
typedef __attribute__((address_space(3))) unsigned int lu32;

static __device__ __forceinline__ float bf2f(unsigned short u){
  unsigned v = ((unsigned)u) << 16;
  return __builtin_bit_cast(float, v);
}
static __device__ __forceinline__ unsigned short f2bf_bits(float f){
  __bf16 h = (__bf16)f;
  return __builtin_bit_cast(unsigned short, h);
}

// ---------------- K0a: build St[s][n] = (sum_e w(s->n)) / max(cnt[n],1) -------
__global__ __launch_bounds__(1024) void k_build_S(const int* __restrict__ ei,
                                                  const float* __restrict__ ea,
                                                  int E, float* __restrict__ St){
  __shared__ float Ssh[40000];
  __shared__ float csh[200];
  __shared__ int nzsh;
  const int t = threadIdx.x;
  if (t == 0) nzsh = 0;
  for (int i = t; i < 40000; i += 1024) Ssh[i] = 0.f;
  if (t < 200) csh[t] = 0.f;
  __syncthreads();
  if (t < 256){ if (ei[2*t + 1] != 0) atomicOr(&nzsh, 1); }
  __syncthreads();
  const int is64 = (nzsh == 0);
  for (int e = t; e < E; e += 1024){
    int s, d;
    if (is64){ s = ei[2*e]; d = ei[2*(E+e)]; }
    else     { s = ei[e];   d = ei[E+e];     }
    if ((unsigned)s < 200u && (unsigned)d < 200u){
      atomicAdd(&Ssh[s*200 + d], ea[e]);
      atomicAdd(&csh[d], 1.f);
    }
  }
  __syncthreads();
  for (int i = t; i < 40000; i += 1024){
    int n = i % 200;
    St[i] = Ssh[i] / fmaxf(csh[n], 1.f);
  }
}

// ---------------- K0b: x (f32) -> Xb (bf16, 256 rows, XOR-swizzled layout) ----
// byte(r,k) = r*32768 + (k/64)*128 + ((slot ^ (r&7))*16) + (k%8)*2, slot=(k%64)/8
__global__ __launch_bounds__(256) void k_xb(const float* __restrict__ x,
                                            unsigned char* __restrict__ Xb){
  int idx0 = blockIdx.x*256 + threadIdx.x;
  for (int idx = idx0; idx < 256*2048; idx += 256*256){
    int r  = idx >> 11;
    int sl = idx & 2047;
    int kc = sl >> 3, s = sl & 7;
    float4 v0 = {0.f,0.f,0.f,0.f}, v1 = {0.f,0.f,0.f,0.f};
    if (r < 200){
      const float* p = x + (size_t)r*16384 + kc*64 + s*8;
      v0 = *(const float4*)p;
      v1 = *(const float4*)(p + 4);
    }
    union { uint4 u; __bf16 h[8]; } pk;
    pk.h[0]=(__bf16)v0.x; pk.h[1]=(__bf16)v0.y; pk.h[2]=(__bf16)v0.z; pk.h[3]=(__bf16)v0.w;
    pk.h[4]=(__bf16)v1.x; pk.h[5]=(__bf16)v1.y; pk.h[6]=(__bf16)v1.z; pk.h[7]=(__bf16)v1.w;
    *(uint4*)(Xb + (size_t)r*32768 + kc*128 + ((s ^ (r & 7)) << 4)) = pk.u;
  }
}

// ---------------- GEMM: Cpart[ks][224][NOUT] = A(224 x K) * [Wl;Wr]^T ----------
// BN=64, 4 waves; wave owns 16 cols x 224 rows (acc[14][1] = 56 VGPR).
// A: single 28KB LDS buffer via global_load_lds (pre-swizzled source).
// B: f32 -> regs (2 alternating sets) -> bf16 frags.
// 4 independent blocks/CU (16 waves/CU), counted vmcnt: issue order per stage
// is A(i+1),B(i+2) so the stage-top wait vmcnt(4) always leaves the next B set
// in flight -> the vm queue never drains during the loop.
template<int KSPLIT, int KDIM, int NOUT, int NITER>
__global__ __launch_bounds__(256, 4) void k_gemm(const unsigned char* __restrict__ Asrc,
                                                 const float* __restrict__ Wl,
                                                 const float* __restrict__ Wr,
                                                 unsigned short* __restrict__ Cpart){
  constexpr int ROWB = KDIM * 2;
  constexpr int NT2  = (NOUT/2) / 64;
  __shared__ unsigned char Abuf[224*128];      // 28672 B

  const int tid  = threadIdx.x;
  const int lane = tid & 63, wid = tid >> 6;
  const int l15  = lane & 15, lk = lane >> 4;
  const int bid  = blockIdx.x;
  const int ks    = bid & (KSPLIT - 1);        // ks%8 = XCD id -> A slice L2-resident
  const int ntile = bid / KSPLIT;
  const float* W = (ntile < NT2) ? (Wl + (size_t)ntile*64*KDIM)
                                 : (Wr + (size_t)(ntile - NT2)*64*KDIM);
  const int kc0   = ks * NITER;
  const int phase = ntile & (NITER - 1);
  auto kcAt = [&](int i){ return kc0 + ((i + phase) & (NITER - 1)); };

  const float* WB = W + (size_t)(wid*16 + l15)*KDIM + lk*8;
  float4 bA[4], bB[4];

  auto issueB = [&](float4 (&b)[4], int kc){
    const float* p = WB + (size_t)kc*64;
    #pragma unroll
    for (int kst = 0; kst < 2; kst++){
      const float* q = p + kst*32;
      b[kst*2 + 0] = *(const float4*)q;
      b[kst*2 + 1] = *(const float4*)(q + 4);
    }
    __builtin_amdgcn_sched_barrier(0);
  };

  const unsigned char* AG = Asrc + (size_t)(tid >> 3)*ROWB + (tid & 7)*16;
  auto issueA = [&](int kc){
    const unsigned char* g = AG + (size_t)kc*128;
    #pragma unroll
    for (int j = 0; j < 7; j++){
      __builtin_amdgcn_global_load_lds(
          (gu32*)(g + (size_t)j*32*ROWB),
          (lu32*)(Abuf + j*4096 + wid*1024),
          16, 0, 0);
    }
    __builtin_amdgcn_sched_barrier(0);
  };

  bf16x8 frag[2];
  auto cvtB = [&](const float4 (&b)[4]){
    #pragma unroll
    for (int f = 0; f < 2; f++){
      float4 lo = b[f*2], hi = b[f*2+1];
      bf16x8 v;
      v[0]=(__bf16)lo.x; v[1]=(__bf16)lo.y; v[2]=(__bf16)lo.z; v[3]=(__bf16)lo.w;
      v[4]=(__bf16)hi.x; v[5]=(__bf16)hi.y; v[6]=(__bf16)hi.z; v[7]=(__bf16)hi.w;
      frag[f] = v;
    }
  };

  f32x4 acc[14];
  #pragma unroll
  for (int mt = 0; mt < 14; mt++) acc[mt] = (f32x4){0.f,0.f,0.f,0.f};

  auto compute = [&](){
    #pragma unroll
    for (int kst = 0; kst < 2; kst++){
      const int sx = (((kst*4 + lk) ^ (l15 & 7)) << 4);
      #pragma unroll
      for (int mt = 0; mt < 14; mt++){
        bf16x8 af = *(const bf16x8*)(Abuf + (mt*16 + l15)*128 + sx);
        acc[mt] = __builtin_amdgcn_mfma_f32_16x16x32_bf16(af, frag[kst], acc[mt], 0, 0, 0);
      }
    }
  };

  auto STAGE = [&](float4 (&bc)[4], int i, bool notlast, bool more){
    if (notlast) asm volatile("s_waitcnt vmcnt(4) lgkmcnt(0)" ::: "memory");
    else         asm volatile("s_waitcnt vmcnt(0) lgkmcnt(0)" ::: "memory");
    __builtin_amdgcn_s_barrier();
    __builtin_amdgcn_sched_barrier(0);
    cvtB(bc);
    compute();
    __builtin_amdgcn_s_barrier();                // all waves done reading Abuf
    __builtin_amdgcn_sched_barrier(0);
    if (notlast) issueA(kcAt(i + 1));            // A before next B (vmcnt order!)
    if (more)    issueB(bc, kcAt(i + 2));
  };

  // prologue: queue = [B(0):4][A(0):7][B(1):4] (same shape as steady state)
  issueB(bA, kcAt(0));
  issueA(kcAt(0));
  issueB(bB, kcAt(1));

  for (int i = 0; i < NITER; i += 2){            // NITER even
    STAGE(bA, i,     true,            i + 2 < NITER);
    STAGE(bB, i + 1, i + 2 < NITER,   i + 3 < NITER);
  }

  // epilogue
  const int rbase = ks * 224;
  const int cbase = ntile*64 + wid*16;
  #pragma unroll
  for (int mt = 0; mt < 14; mt++)
    #pragma unroll
    for (int j = 0; j < 4; j++){
      int row = mt*16 + lk*4 + j;
      Cpart[(size_t)(rbase + row)*NOUT + cbase + l15] = f2bf_bits(acc[mt][j]);
    }
}

// ---------------- h1 = relu(S@P + Q + b1), P/Q reduced from Cp1 on the fly -----
__global__ __launch_bounds__(256) void k_h1f(const unsigned short* __restrict__ Cp1,
                                             const float* __restrict__ St,
                                             const float* __restrict__ b1,
                                             unsigned char* __restrict__ H1b){
  __shared__ float Ssh[200*50];
  const int och = blockIdx.x >> 2, nsp = blockIdx.x & 3;
  const int t = threadIdx.x;
  for (int i = t; i < 200*50; i += 256){
    int s = i / 50, j = i - s*50;
    Ssh[i] = St[s*200 + nsp*50 + j];
  }
  __syncthreads();
  const int w = t >> 6, lane = t & 63;
  const int o = och*64 + lane;                 // P column (0..4095)
  const int jb = w*13;
  const int jn = (w == 3) ? 11 : 13;
  constexpr size_t PART = (size_t)224*8192;
  const unsigned short* P = Cp1 + o;
  float acc[13];
  #pragma unroll
  for (int i = 0; i < 13; i++) acc[i] = 0.f;
  #pragma unroll 2
  for (int s = 0; s < 200; s++){
    float p = 0.f;
    #pragma unroll
    for (int ksi = 0; ksi < 8; ksi++)
      p += bf2f(P[(size_t)ksi*PART + (size_t)s*8192]);
    #pragma unroll
    for (int i = 0; i < 13; i++)
      if (i < jn) acc[i] = fmaf(Ssh[s*50 + jb + i], p, acc[i]);
  }
  float bo = b1[o];
  #pragma unroll
  for (int i = 0; i < 13; i++)
    if (i < jn){
      int r = nsp*50 + jb + i;
      float q = 0.f;
      #pragma unroll
      for (int ksi = 0; ksi < 8; ksi++)
        q += bf2f(Cp1[(size_t)ksi*PART + (size_t)r*8192 + 4096 + o]);
      float h = fmaxf(acc[i] + q + bo, 0.f);
      int kc = o >> 6, wi = o & 63, slot = wi >> 3, rem = wi & 7;
      *(__bf16*)(H1b + (size_t)r*8192 + kc*128 + (((slot ^ (r & 7)) << 4) | (rem*2))) = (__bf16)h;
    }
}

// ---------------- h2 = S@R + T + b2, R/T reduced from Cp2 on the fly -----------
__global__ __launch_bounds__(256) void k_h2f(const unsigned short* __restrict__ Cp2,
                                             const float* __restrict__ St,
                                             const float* __restrict__ b2,
                                             float* __restrict__ h2){
  __shared__ float Ssh[200*13];
  const int cch = blockIdx.x >> 4, nsp = blockIdx.x & 15;
  const int nb0 = nsp * 13;
  const int t = threadIdx.x;
  for (int i = t; i < 200*13; i += 256){
    int s = i / 13, j = i - s*13;
    int g = nb0 + j;
    Ssh[i] = (g < 200) ? St[s*200 + g] : 0.f;
  }
  __syncthreads();
  const int w = t >> 6, lane = t & 63;
  const int c = cch*64 + lane;                 // R column (0..511)
  constexpr size_t PART = (size_t)224*1024;
  const unsigned short* R = Cp2 + c;
  float acc[4] = {0.f, 0.f, 0.f, 0.f};
  #pragma unroll 2
  for (int s = 0; s < 200; s++){
    float rv = 0.f;
    #pragma unroll
    for (int ksi = 0; ksi < 8; ksi++)
      rv += bf2f(R[(size_t)ksi*PART + (size_t)s*1024]);
    #pragma unroll
    for (int ii = 0; ii < 4; ii++){
      int j = w*4 + ii;
      if (j < 13 && nb0 + j < 200)
        acc[ii] = fmaf(Ssh[s*13 + j], rv, acc[ii]);
    }
  }
  float bc = b2[c];
  #pragma unroll
  for (int ii = 0; ii < 4; ii++){
    int j = w*4 + ii;
    if (j < 13 && nb0 + j < 200){
      int n = nb0 + j;
      float tv = 0.f;
      #pragma unroll
      for (int ksi = 0; ksi < 8; ksi++)
        tv += bf2f(Cp2[(size_t)ksi*PART + (size_t)n*1024 + 512 + c]);
      h2[(size_t)n*512 + c] = acc[ii] + tv + bc;
    }
  }
}

// ---------------- classifier: out[512,10] = mlp(h2^T) --------------------------
__global__ __launch_bounds__(512) void k_cls(const float* __restrict__ h2,
    const float* __restrict__ Wc1, const float* __restrict__ bc1,
    const float* __restrict__ Wc2, const float* __restrict__ bc2,
    const float* __restrict__ Wc3, const float* __restrict__ bc3,
    float* __restrict__ out){
  __shared__ float zt[64*201];
  __shared__ float z1[64*101];
  __shared__ float z2[64*51];
  const int cb = blockIdx.x * 64;
  const int t = threadIdx.x;
  for (int idx = t; idx < 64*200; idx += 512){
    int n = idx >> 6, cl = idx & 63;
    zt[cl*201 + n] = h2[(size_t)n*512 + cb + cl];
  }
  __syncthreads();
  const int w = t >> 6, c = t & 63;
  {
    const int jb = __builtin_amdgcn_readfirstlane(w*13);
    const int jn = (w == 7) ? 9 : 13;
    float a[13];
    #pragma unroll
    for (int j = 0; j < 13; j++) a[j] = (j < jn) ? bc1[jb + j] : 0.f;
    for (int n = 0; n < 200; n++){
      float v = zt[c*201 + n];
      #pragma unroll
      for (int j = 0; j < 13; j++)
        if (j < jn) a[j] = fmaf(v, Wc1[(jb + j)*200 + n], a[j]);
    }
    #pragma unroll
    for (int j = 0; j < 13; j++)
      if (j < jn) z1[c*101 + jb + j] = fmaxf(a[j], 0.f);
  }
  __syncthreads();
  {
    const int jb = __builtin_amdgcn_readfirstlane(w*7);
    const int jn = (w == 7) ? 1 : 7;
    float a[7];
    #pragma unroll
    for (int j = 0; j < 7; j++) a[j] = (j < jn) ? bc2[jb + j] : 0.f;
    for (int n = 0; n < 100; n++){
      float v = z1[c*101 + n];
      #pragma unroll
      for (int j = 0; j < 7; j++)
        if (j < jn) a[j] = fmaf(v, Wc2[(jb + j)*100 + n], a[j]);
    }
    #pragma unroll
    for (int j = 0; j < 7; j++)
      if (j < jn) z2[c*51 + jb + j] = fmaxf(a[j], 0.f);
  }
  __syncthreads();
  if (w < 5){
    const int jb = __builtin_amdgcn_readfirstlane(w*2);
    float a[2] = { bc3[jb], bc3[jb + 1] };
    for (int n = 0; n < 50; n++){
      float v = z2[c*51 + n];
      a[0] = fmaf(v, Wc3[jb*50 + n], a[0]);
      a[1] = fmaf(v, Wc3[(jb + 1)*50 + n], a[1]);
    }
    out[(size_t)(cb + c)*10 + jb]     = a[0];
    out[(size_t)(cb + c)*10 + jb + 1] = a[1];
  }
}

// ---------------- host launch ---------------------------------------------------
extern "C" void kernel_launch(void* const* d_in, const int* in_sizes, int n_in,
                              void* d_out, int out_size, void* d_ws, size_t ws_size,
                              hipStream_t stream){
  (void)n_in; (void)out_size; (void)ws_size;
  const float* x   = (const float*)d_in[0];
  const int*   ei  = (const int*)  d_in[1];
  const float* ea  = (const float*)d_in[2];
  const float* W1l = (const float*)d_in[3];
  const float* W1r = (const float*)d_in[4];
  const float* b1  = (const float*)d_in[5];
  const float* W2l = (const float*)d_in[6];
  const float* W2r = (const float*)d_in[7];
  const float* b2  = (const float*)d_in[8];
  const float* Wc1 = (const float*)d_in[9];
  const float* bc1 = (const float*)d_in[10];
  const float* Wc2 = (const float*)d_in[11];
  const float* bc2 = (const float*)d_in[12];
  const float* Wc3 = (const float*)d_in[13];
  const float* bc3 = (const float*)d_in[14];
  float* out = (float*)d_out;
  char* ws = (char*)d_ws;
  const int E = in_sizes[1] / 2;

  constexpr size_t ST_OFF  = 0;                                   // 160000
  constexpr size_t XB_OFF  = 262144;                              // 8 MiB
  constexpr size_t CP1_OFF = XB_OFF + (size_t)256*16384*2;        // 8 x 224 x 8192 bf16
  constexpr size_t H1B_OFF = CP1_OFF + (size_t)8*224*8192*2;      // 256 x 4096 bf16
  constexpr size_t CP2_OFF = H1B_OFF + (size_t)256*4096*2;        // 8 x 224 x 1024 bf16
  constexpr size_t H2_OFF  = CP2_OFF + (size_t)8*224*1024*2;      // 200 x 512 f32

  float*          St  = (float*)(ws + ST_OFF);
  unsigned char*  Xb  = (unsigned char*)(ws + XB_OFF);
  unsigned short* Cp1 = (unsigned short*)(ws + CP1_OFF);
  unsigned char*  H1b = (unsigned char*)(ws + H1B_OFF);
  unsigned short* Cp2 = (unsigned short*)(ws + CP2_OFF);
  float*          h2  = (float*)(ws + H2_OFF);

  k_build_S<<<dim3(1),   dim3(1024), 0, stream>>>(ei, ea, E, St);
  k_xb     <<<dim3(256), dim3(256),  0, stream>>>(x, Xb);
  // GEMM1: BN=64, KS=8, NITER = 16384/64/8 = 32, grid = 128*8 = 1024 (4 blk/CU)
  k_gemm<8, 16384, 8192, 32><<<dim3(1024), dim3(256), 0, stream>>>(Xb, W1l, W1r, Cp1);
  k_h1f    <<<dim3(256), dim3(256),  0, stream>>>(Cp1, St, b1, H1b);
  // GEMM2: BN=64, KS=8, NITER = 4096/64/8 = 8, grid = 16*8 = 128
  k_gemm<8, 4096, 1024, 8><<<dim3(128), dim3(256), 0, stream>>>(H1b, W2l, W2r, Cp2);
  k_h2f    <<<dim3(128), dim3(256),  0, stream>>>(Cp2, St, b2, h2);
  k_cls    <<<dim3(8),   dim3(512),  0, stream>>>(h2, Wc1, bc1, Wc2, bc2, Wc3, bc3, out);
}

// Round 11
// 433.770 us; speedup vs baseline: 1.4206x; 1.4206x over previous
//
#include <hip/hip_runtime.h>
#include <hip/hip_bf16.h>
#include <cstdint>
#include <cstddef>

typedef __bf16 bf16x8 __attribute__((ext_vector_type(8)));
typedef float  f32x4  __attribute__((ext_vector_type(4)));

typedef const __attribute__((address_space(1))) unsigned int gu32;
typedef __attribute__((address_space(3))) unsigned int lu32;

static __device__ __forceinline__ float bf2f(unsigned short u){
  unsigned v = ((unsigned)u) << 16;
  return __builtin_bit_cast(float, v);
}
static __device__ __forceinline__ unsigned short f2bf_bits(float f){
  __bf16 h = (__bf16)f;
  return __builtin_bit_cast(unsigned short, h);
}

// ---- K0a: scatter edges -> Straw[s][n] = sum w(s->n); rcnt[n] = 1/max(cnt,1) --
// grid 25: block b owns source rows [8b, 8b+8). Full-row writes (no global init).
__global__ __launch_bounds__(1024) void k_scatter(const int* __restrict__ ei,
                                                  const float* __restrict__ ea,
                                                  int E, float* __restrict__ Straw,
                                                  float* __restrict__ rcnt){
  __shared__ float Ssh[8*200];
  __shared__ float csh[200];
  __shared__ int nzsh;
  const int t = threadIdx.x;
  const int s0 = blockIdx.x * 8;
  if (t == 0) nzsh = 0;
  for (int i = t; i < 1600; i += 1024) Ssh[i] = 0.f;
  if (t < 200) csh[t] = 0.f;
  __syncthreads();
  if (t < 256){ if (ei[2*t + 1] != 0) atomicOr(&nzsh, 1); }
  __syncthreads();
  const int is64 = (nzsh == 0);
  const bool do_cnt = (blockIdx.x == 0);
  for (int e = t; e < E; e += 1024){
    int s, d;
    if (is64){ s = ei[2*e]; d = ei[2*(E+e)]; }
    else     { s = ei[e];   d = ei[E+e];     }
    if ((unsigned)s < 200u && (unsigned)d < 200u){
      if (do_cnt) atomicAdd(&csh[d], 1.f);
      unsigned ls = (unsigned)(s - s0);
      if (ls < 8u) atomicAdd(&Ssh[ls*200 + d], ea[e]);
    }
  }
  __syncthreads();
  for (int i = t; i < 1600; i += 1024)
    Straw[(size_t)s0*200 + i] = Ssh[i];
  if (do_cnt && t < 200) rcnt[t] = 1.f / fmaxf(csh[t], 1.f);
}

// ---------------- K0b: x (f32) -> Xb (bf16, 256 rows, XOR-swizzled layout) ----
// byte(r,k) = r*32768 + (k/64)*128 + ((slot ^ (r&7))*16) + (k%8)*2, slot=(k%64)/8
__global__ __launch_bounds__(256) void k_xb(const float* __restrict__ x,
                                            unsigned char* __restrict__ Xb){
  int idx0 = blockIdx.x*256 + threadIdx.x;
  for (int idx = idx0; idx < 256*2048; idx += 256*256){
    int r  = idx >> 11;
    int sl = idx & 2047;
    int kc = sl >> 3, s = sl & 7;
    float4 v0 = {0.f,0.f,0.f,0.f}, v1 = {0.f,0.f,0.f,0.f};
    if (r < 200){
      const float* p = x + (size_t)r*16384 + kc*64 + s*8;
      v0 = *(const float4*)p;
      v1 = *(const float4*)(p + 4);
    }
    union { uint4 u; __bf16 h[8]; } pk;
    pk.h[0]=(__bf16)v0.x; pk.h[1]=(__bf16)v0.y; pk.h[2]=(__bf16)v0.z; pk.h[3]=(__bf16)v0.w;
    pk.h[4]=(__bf16)v1.x; pk.h[5]=(__bf16)v1.y; pk.h[6]=(__bf16)v1.z; pk.h[7]=(__bf16)v1.w;
    *(uint4*)(Xb + (size_t)r*32768 + kc*128 + ((s ^ (r & 7)) << 4)) = pk.u;
  }
}

// ---------------- GEMM: Cpart[ks][224][NOUT] = A(224 x K) * [Wl;Wr]^T ----------
// R8 structure (best measured): BN=128, BK=64, 4 waves, wave owns 32 cols.
// B: f32 -> regs (NON-TEMPORAL: stream W around L2/L3, keep caches for A),
// double-buffered. A: global_load_lds pre-swizzled, LDS 2x28KB.
// Counted vmcnt(15): the vm queue never drains during the loop.
template<int BN, int KSPLIT, int KDIM, int NOUT, int NITER>
__global__ __launch_bounds__(256, 2) void k_gemm(const unsigned char* __restrict__ Asrc,
                                                 const float* __restrict__ Wl,
                                                 const float* __restrict__ Wr,
                                                 unsigned short* __restrict__ Cpart){
  constexpr int ROWB = KDIM * 2;
  constexpr int NT2  = (NOUT/2) / BN;
  constexpr int NS   = BN / 64;            // 16-col strips per wave (=2)
  constexpr int NB   = NS * 2 * 2;         // f32x4 staging per set (=8)
  __shared__ unsigned char Lds[2][224*128];

  const int tid  = threadIdx.x;
  const int lane = tid & 63, wid = tid >> 6;
  const int l15  = lane & 15, lk = lane >> 4;
  const int bid  = blockIdx.x;
  const int ks    = bid & (KSPLIT - 1);    // ks%8 = XCD id -> A slice L2-resident
  const int ntile = bid / KSPLIT;
  const float* W = (ntile < NT2) ? (Wl + (size_t)ntile*BN*KDIM)
                                 : (Wr + (size_t)(ntile - NT2)*BN*KDIM);
  const int kc0   = ks * NITER;
  const int phase = ntile & (NITER - 1);
  auto kcAt = [&](int i){ return kc0 + ((i + phase) & (NITER - 1)); };

  const float* WB = W + (size_t)(wid*32 + l15)*KDIM + lk*8;
  f32x4 b0[NB], b1[NB];

  auto issueB = [&](f32x4 (&b)[NB], int kc){
    const float* p = WB + (size_t)kc*64;
    #pragma unroll
    for (int ns = 0; ns < NS; ns++)
      #pragma unroll
      for (int kst = 0; kst < 2; kst++){
        const f32x4* q = (const f32x4*)(p + (size_t)ns*16*KDIM + kst*32);
        b[(ns*2+kst)*2 + 0] = __builtin_nontemporal_load(q);
        b[(ns*2+kst)*2 + 1] = __builtin_nontemporal_load(q + 1);
      }
    __builtin_amdgcn_sched_barrier(0);
  };

  const unsigned char* AG = Asrc + (size_t)(tid >> 3)*ROWB + (tid & 7)*16;
  auto issueA = [&](unsigned char* buf, int kc){
    const unsigned char* g = AG + (size_t)kc*128;
    #pragma unroll
    for (int j = 0; j < 7; j++){
      __builtin_amdgcn_global_load_lds(
          (gu32*)(g + (size_t)j*32*ROWB),
          (lu32*)(buf + j*4096 + wid*1024),
          16, 0, 0);
    }
    __builtin_amdgcn_sched_barrier(0);
  };

  bf16x8 frag[NS*2];
  auto cvtB = [&](const f32x4 (&b)[NB]){
    #pragma unroll
    for (int f = 0; f < NS*2; f++){
      f32x4 lo = b[f*2], hi = b[f*2+1];
      bf16x8 v;
      v[0]=(__bf16)lo[0]; v[1]=(__bf16)lo[1]; v[2]=(__bf16)lo[2]; v[3]=(__bf16)lo[3];
      v[4]=(__bf16)hi[0]; v[5]=(__bf16)hi[1]; v[6]=(__bf16)hi[2]; v[7]=(__bf16)hi[3];
      frag[f] = v;
    }
  };

  f32x4 acc[14][NS];
  #pragma unroll
  for (int mt = 0; mt < 14; mt++)
    #pragma unroll
    for (int ns = 0; ns < NS; ns++)
      acc[mt][ns] = (f32x4){0.f,0.f,0.f,0.f};

  auto compute = [&](const unsigned char* buf){
    #pragma unroll
    for (int kst = 0; kst < 2; kst++){
      const int sx = (((kst*4 + lk) ^ (l15 & 7)) << 4);
      #pragma unroll
      for (int mt = 0; mt < 14; mt++){
        bf16x8 af = *(const bf16x8*)(buf + (mt*16 + l15)*128 + sx);
        #pragma unroll
        for (int ns = 0; ns < NS; ns++)
          acc[mt][ns] = __builtin_amdgcn_mfma_f32_16x16x32_bf16(af, frag[ns*2+kst], acc[mt][ns], 0, 0, 0);
      }
    }
  };

  auto STAGE = [&](f32x4 (&bc)[NB], unsigned char* Lc, int i){
    if (i + 1 < NITER) asm volatile("s_waitcnt vmcnt(15) lgkmcnt(0)" ::: "memory");
    else               asm volatile("s_waitcnt vmcnt(0) lgkmcnt(0)" ::: "memory");
    __builtin_amdgcn_s_barrier();
    __builtin_amdgcn_sched_barrier(0);
    cvtB(bc);
    if (i + 2 < NITER) issueB(bc, kcAt(i + 2));
    __builtin_amdgcn_sched_barrier(0);
    compute(Lc);
    __builtin_amdgcn_s_barrier();
    __builtin_amdgcn_sched_barrier(0);
    if (i + 2 < NITER) issueA(Lc, kcAt(i + 2));
  };

  issueB(b0, kcAt(0)); issueA(Lds[0], kcAt(0));
  issueB(b1, kcAt(1)); issueA(Lds[1], kcAt(1));

  for (int i = 0; i < NITER; i += 2){
    STAGE(b0, Lds[0], i);
    STAGE(b1, Lds[1], i + 1);
  }

  const int rbase = ks * 224;
  const int cbase = ntile*BN + wid*32;
  #pragma unroll
  for (int mt = 0; mt < 14; mt++)
    #pragma unroll
    for (int ns = 0; ns < NS; ns++)
      #pragma unroll
      for (int j = 0; j < 4; j++){
        int row = mt*16 + lk*4 + j;
        int col = cbase + ns*16 + l15;
        Cpart[(size_t)(rbase + row)*NOUT + col] = f2bf_bits(acc[mt][ns][j]);
      }
}

// ---------------- reduce K partials (bf16) -> f32 ------------------------------
template<int KS>
__global__ __launch_bounds__(256) void k_reduce(const unsigned short* __restrict__ cp,
                                                float* __restrict__ out, int n8){
  const size_t part = (size_t)n8 * 8;
  int stride = gridDim.x * blockDim.x;
  for (int idx = blockIdx.x*blockDim.x + threadIdx.x; idx < n8; idx += stride){
    float a[8] = {0.f,0.f,0.f,0.f,0.f,0.f,0.f,0.f};
    #pragma unroll
    for (int ksi = 0; ksi < KS; ksi++){
      union { uint4 v; unsigned short s[8]; } u;
      u.v = *(const uint4*)(cp + ksi*part + (size_t)idx*8);
      #pragma unroll
      for (int j = 0; j < 8; j++) a[j] += bf2f(u.s[j]);
    }
    float4 lo = {a[0],a[1],a[2],a[3]};
    float4 hi = {a[4],a[5],a[6],a[7]};
    *(float4*)(out + (size_t)idx*8)     = lo;
    *(float4*)(out + (size_t)idx*8 + 4) = hi;
  }
}

// ---------------- h1 = relu(S@P + Q + b1) -> H1b (swizzled bf16) ---------------
// St slice staged in LDS with rcnt divide folded in; s-loop unroll 4 for MLP.
__global__ __launch_bounds__(256) void k_h1(const float* __restrict__ PQ,
                                            const float* __restrict__ Straw,
                                            const float* __restrict__ rcnt,
                                            const float* __restrict__ b1,
                                            unsigned char* __restrict__ H1b){
  __shared__ float Ssh[200*50];
  __shared__ float rcl[50];
  const int och = blockIdx.x >> 2, nsp = blockIdx.x & 3;
  const int t = threadIdx.x;
  if (t < 50) rcl[t] = rcnt[nsp*50 + t];
  __syncthreads();
  for (int i = t; i < 200*50; i += 256){
    int s = i / 50, j = i - s*50;
    Ssh[i] = Straw[s*200 + nsp*50 + j] * rcl[j];
  }
  __syncthreads();
  const int w = t >> 6, lane = t & 63;
  const int o = och*64 + lane;
  const int jb = w*13;
  const int jn = (w == 3) ? 11 : 13;
  float acc[13];
  #pragma unroll
  for (int i = 0; i < 13; i++) acc[i] = 0.f;
  #pragma unroll 4
  for (int s = 0; s < 200; s++){
    float p = PQ[(size_t)s*8192 + o];
    #pragma unroll
    for (int i = 0; i < 13; i++)
      if (i < jn) acc[i] = fmaf(Ssh[s*50 + jb + i], p, acc[i]);
  }
  float bo = b1[o];
  #pragma unroll
  for (int i = 0; i < 13; i++)
    if (i < jn){
      int r = nsp*50 + jb + i;
      float h = acc[i] + PQ[(size_t)r*8192 + 4096 + o] + bo;
      h = fmaxf(h, 0.f);
      int kc = o >> 6, wi = o & 63, slot = wi >> 3, rem = wi & 7;
      *(__bf16*)(H1b + (size_t)r*8192 + kc*128 + (((slot ^ (r & 7)) << 4) | (rem*2))) = (__bf16)h;
    }
}

// ---------------- h2 = S@R + T + b2 (no relu) ----------------------------------
__global__ __launch_bounds__(256) void k_h2(const float* __restrict__ RT,
                                            const float* __restrict__ Straw,
                                            const float* __restrict__ rcnt,
                                            const float* __restrict__ b2,
                                            float* __restrict__ h2){
  __shared__ float Ssh[200*13];
  __shared__ float rcl[13];
  const int cch = blockIdx.x >> 4, nsp = blockIdx.x & 15;
  const int nb0 = nsp * 13;
  const int t = threadIdx.x;
  if (t < 13) rcl[t] = (nb0 + t < 200) ? rcnt[nb0 + t] : 0.f;
  __syncthreads();
  for (int i = t; i < 200*13; i += 256){
    int s = i / 13, j = i - s*13;
    int g = nb0 + j;
    Ssh[i] = (g < 200) ? Straw[s*200 + g] * rcl[j] : 0.f;
  }
  __syncthreads();
  const int w = t >> 6, lane = t & 63;
  const int c = cch*64 + lane;
  float acc[4] = {0.f, 0.f, 0.f, 0.f};
  #pragma unroll 4
  for (int s = 0; s < 200; s++){
    float r = RT[(size_t)s*1024 + c];
    #pragma unroll
    for (int ii = 0; ii < 4; ii++){
      int j = w*4 + ii;
      if (j < 13 && nb0 + j < 200)
        acc[ii] = fmaf(Ssh[s*13 + j], r, acc[ii]);
    }
  }
  float bc = b2[c];
  #pragma unroll
  for (int ii = 0; ii < 4; ii++){
    int j = w*4 + ii;
    if (j < 13 && nb0 + j < 200){
      int n = nb0 + j;
      h2[(size_t)n*512 + c] = acc[ii] + RT[(size_t)n*1024 + 512 + c] + bc;
    }
  }
}

// ---------------- classifier: out[512,10] = mlp(h2^T) --------------------------
__global__ __launch_bounds__(512) void k_cls(const float* __restrict__ h2,
    const float* __restrict__ Wc1, const float* __restrict__ bc1,
    const float* __restrict__ Wc2, const float* __restrict__ bc2,
    const float* __restrict__ Wc3, const float* __restrict__ bc3,
    float* __restrict__ out){
  __shared__ float zt[64*201];
  __shared__ float z1[64*101];
  __shared__ float z2[64*51];
  const int cb = blockIdx.x * 64;
  const int t = threadIdx.x;
  for (int idx = t; idx < 64*200; idx += 512){
    int n = idx >> 6, cl = idx & 63;
    zt[cl*201 + n] = h2[(size_t)n*512 + cb + cl];
  }
  __syncthreads();
  const int w = t >> 6, c = t & 63;
  {
    const int jb = __builtin_amdgcn_readfirstlane(w*13);
    const int jn = (w == 7) ? 9 : 13;
    float a[13];
    #pragma unroll
    for (int j = 0; j < 13; j++) a[j] = (j < jn) ? bc1[jb + j] : 0.f;
    for (int n = 0; n < 200; n++){
      float v = zt[c*201 + n];
      #pragma unroll
      for (int j = 0; j < 13; j++)
        if (j < jn) a[j] = fmaf(v, Wc1[(jb + j)*200 + n], a[j]);
    }
    #pragma unroll
    for (int j = 0; j < 13; j++)
      if (j < jn) z1[c*101 + jb + j] = fmaxf(a[j], 0.f);
  }
  __syncthreads();
  {
    const int jb = __builtin_amdgcn_readfirstlane(w*7);
    const int jn = (w == 7) ? 1 : 7;
    float a[7];
    #pragma unroll
    for (int j = 0; j < 7; j++) a[j] = (j < jn) ? bc2[jb + j] : 0.f;
    for (int n = 0; n < 100; n++){
      float v = z1[c*101 + n];
      #pragma unroll
      for (int j = 0; j < 7; j++)
        if (j < jn) a[j] = fmaf(v, Wc2[(jb + j)*100 + n], a[j]);
    }
    #pragma unroll
    for (int j = 0; j < 7; j++)
      if (j < jn) z2[c*51 + jb + j] = fmaxf(a[j], 0.f);
  }
  __syncthreads();
  if (w < 5){
    const int jb = __builtin_amdgcn_readfirstlane(w*2);
    float a[2] = { bc3[jb], bc3[jb + 1] };
    for (int n = 0; n < 50; n++){
      float v = z2[c*51 + n];
      a[0] = fmaf(v, Wc3[jb*50 + n], a[0]);
      a[1] = fmaf(v, Wc3[(jb + 1)*50 + n], a[1]);
    }
    out[(size_t)(cb + c)*10 + jb]     = a[0];
    out[(size_t)(cb + c)*10 + jb + 1] = a[1];
  }
}

// ---------------- host launch ---------------------------------------------------
extern "C" void kernel_launch(void* const* d_in, const int* in_sizes, int n_in,
                              void* d_out, int out_size, void* d_ws, size_t ws_size,
                              hipStream_t stream){
  (void)n_in; (void)out_size; (void)ws_size;
  const float* x   = (const float*)d_in[0];
  const int*   ei  = (const int*)  d_in[1];
  const float* ea  = (const float*)d_in[2];
  const float* W1l = (const float*)d_in[3];
  const float* W1r = (const float*)d_in[4];
  const float* b1  = (const float*)d_in[5];
  const float* W2l = (const float*)d_in[6];
  const float* W2r = (const float*)d_in[7];
  const float* b2  = (const float*)d_in[8];
  const float* Wc1 = (const float*)d_in[9];
  const float* bc1 = (const float*)d_in[10];
  const float* Wc2 = (const float*)d_in[11];
  const float* bc2 = (const float*)d_in[12];
  const float* Wc3 = (const float*)d_in[13];
  const float* bc3 = (const float*)d_in[14];
  float* out = (float*)d_out;
  char* ws = (char*)d_ws;
  const int E = in_sizes[1] / 2;

  constexpr size_t ST_OFF  = 0;                                   // 160000 (Straw)
  constexpr size_t RC_OFF  = 160000;                              // 800 (rcnt)
  constexpr size_t XB_OFF  = 262144;                              // 8 MiB
  constexpr size_t CP1_OFF = XB_OFF + (size_t)256*16384*2;        // 8 x 224 x 8192 bf16
  constexpr size_t PQ_OFF  = CP1_OFF + (size_t)8*224*8192*2;      // 224 x 8192 f32
  constexpr size_t H1B_OFF = PQ_OFF + (size_t)224*8192*4;         // 256 x 4096 bf16
  constexpr size_t CP2_OFF = H1B_OFF + (size_t)256*4096*2;        // 32 x 224 x 1024 bf16
  constexpr size_t RT_OFF  = CP2_OFF + (size_t)32*224*1024*2;     // 224 x 1024 f32
  constexpr size_t H2_OFF  = RT_OFF + (size_t)224*1024*4;         // 200 x 512 f32

  float*          St  = (float*)(ws + ST_OFF);
  float*          rc  = (float*)(ws + RC_OFF);
  unsigned char*  Xb  = (unsigned char*)(ws + XB_OFF);
  unsigned short* Cp1 = (unsigned short*)(ws + CP1_OFF);
  float*          PQ  = (float*)(ws + PQ_OFF);
  unsigned char*  H1b = (unsigned char*)(ws + H1B_OFF);
  unsigned short* Cp2 = (unsigned short*)(ws + CP2_OFF);
  float*          RT  = (float*)(ws + RT_OFF);
  float*          h2  = (float*)(ws + H2_OFF);

  k_scatter<<<dim3(25),  dim3(1024), 0, stream>>>(ei, ea, E, St, rc);
  k_xb     <<<dim3(256), dim3(256),  0, stream>>>(x, Xb);
  // GEMM1: BN=128, KS=8, NITER=32, grid 512 (2 blocks/CU)
  k_gemm<128, 8, 16384, 8192, 32><<<dim3(512), dim3(256), 0, stream>>>(Xb, W1l, W1r, Cp1);
  k_reduce<8> <<<dim3(1024), dim3(256), 0, stream>>>(Cp1, PQ, 224*8192/8);
  k_h1     <<<dim3(256), dim3(256),  0, stream>>>(PQ, St, rc, b1, H1b);
  // GEMM2: BN=128, KS=32, NITER=2, grid 256
  k_gemm<128, 32, 4096, 1024, 2><<<dim3(256), dim3(256), 0, stream>>>(H1b, W2l, W2r, Cp2);
  k_reduce<32><<<dim3(256), dim3(256), 0, stream>>>(Cp2, RT, 224*1024/8);
  k_h2     <<<dim3(128), dim3(256),  0, stream>>>(RT, St, rc, b2, h2);
  k_cls    <<<dim3(8),   dim3(512),  0, stream>>>(h2, Wc1, bc1, Wc2, bc2, Wc3, bc3, out);
}